// Round 13
// baseline (139.290 us; speedup 1.0000x reference)
//
#include <hip/hip_runtime.h>

#define LSEQ 1024
#define INDIM 256
#define DM 32
#define PD 64
#define JT 256
#define NJT (LSEQ / JT)   // 4

typedef float f32x4 __attribute__((ext_vector_type(4)));

__device__ __forceinline__ void fma4(f32x4& a, float s, const f32x4& t) {
  a.x = fmaf(s, t.x, a.x); a.y = fmaf(s, t.y, a.y);
  a.z = fmaf(s, t.z, a.z); a.w = fmaf(s, t.w, a.w);
}

__device__ __forceinline__ void g2l16(const float* g, float* l) {
  __builtin_amdgcn_global_load_lds(
      (__attribute__((address_space(1))) void*)g,
      (__attribute__((address_space(3))) void*)l, 16, 0, 0);
}

// Prep: projection only (no t).  s[i][c] = seq[i,:]@W1[:,c] + b1[c] -> sT[c][i]
__global__ __launch_bounds__(256) void k_proj(const float* __restrict__ seq,
    const float* __restrict__ W1, const float* __restrict__ b1,
    float* __restrict__ sT) {
  int i0 = blockIdx.x * 4;
  int tid = threadIdx.x;
  __shared__ float srow[4][INDIM];
  __shared__ float part[4][2][DM];
  ((f32x4*)&srow[0][0])[tid] =
      ((const f32x4*)(seq + (size_t)i0 * INDIM))[tid];
  __syncthreads();
  {
    int c = tid & 31, dseg = (tid >> 5) & 1, il = tid >> 6;
    float a = 0.f;
    #pragma unroll 16
    for (int d = 0; d < 128; ++d)
      a = fmaf(srow[il][dseg * 128 + d], W1[(dseg * 128 + d) * DM + c], a);
    part[il][dseg][c] = a;
  }
  __syncthreads();
  if (tid < 128) {
    int il = tid >> 5, c = tid & 31;
    sT[c * LSEQ + i0 + il] = b1[c] + part[il][0][c] + part[il][1][c];
  }
}

// Main: champion R12 phase order, with t computed IN-BLOCK from W2 (L2):
//   sish stage -> barrier -> t-compute (W2 f32x4 L2 loads, consumed here)
//   -> g2l s staging -> barrier (drains only consumed/W2/g2l; pf NOT issued)
//   -> nt pair loads -> c-loop -> plain-store epilogue.
__global__ __launch_bounds__(256, 4) void k_main(const float* __restrict__ sT,
    const float* __restrict__ W2, const float* __restrict__ b2,
    const float* __restrict__ pair, float* __restrict__ out) {
  __shared__ float t_lds[DM][PD];    // 8 KB
  __shared__ float s_lds[DM][JT];    // 32 KB -> 40 KB total, 4 blocks/CU
  __shared__ float sish[DM];
  int tid = threadIdx.x;
  // XCD-chunked bijective swizzle (4096 % 8 == 0): XCD k gets i-band
  // [k*128,(k+1)*128) -> W2 + sT hot in every XCD's L2; same-i blocks adjacent.
  int bid = ((blockIdx.x & 7) << 9) + (blockIdx.x >> 3);
  int i = bid >> 2;
  int jt = (bid & (NJT - 1)) * JT;
  int pl = tid & 7;           // p = pl*4..+3 and 32+pl*4..+3
  int jg = tid >> 3;          // 0..31: j = jt + jg*8 + jj
  int lane = tid & 63, w = tid >> 6;

  // 0) stage s[i][:]
  if (tid < DM) sish[tid] = sT[tid * LSEQ + i];
  __syncthreads();

  // 1) t-compute: thread = (c = tid>>3, p8 = tid&7) owns t[c][p8*8..+8]
  {
    int c = tid >> 3, p8 = tid & 7;
    const f32x4* w2v = (const f32x4*)(W2 + (size_t)(c * DM) * PD + p8 * 8);
    f32x4 a0 = (f32x4)(0.f), a1 = (f32x4)(0.f);
    #pragma unroll 4
    for (int d = 0; d < DM; ++d) {
      float sv = sish[d];
      f32x4 wA = w2v[d * 16];       // W2[(c*32+d)*64 + p8*8 .. +3]
      f32x4 wB = w2v[d * 16 + 1];   // .. +4..+7
      fma4(a0, sv, wA);
      fma4(a1, sv, wB);
    }
    *(f32x4*)&t_lds[c][p8 * 8] = a0;
    *(f32x4*)&t_lds[c][p8 * 8 + 4] = a1;
  }

  // 2) async s-tile staging from L2-resident sT
  {
    const float* sb = sT + (size_t)(w * 8) * LSEQ + jt + lane * 4;
    float* sl = &s_lds[w * 8][0];
    #pragma unroll
    for (int q = 0; q < 8; ++q)
      g2l16(sb + q * LSEQ, sl + q * JT);
  }
  __syncthreads();   // drains g2l (L2-fast); W2 loads already consumed; pf not issued

  // 3) NOW issue pair loads (nontemporal); nothing below drains until epilogue
  size_t rowbase = (size_t)i * (LSEQ * PD) + (size_t)(jt + jg * 8) * PD;
  const f32x4* pp = (const f32x4*)(pair + rowbase);
  f32x4 pf0[8], pf1[8];
  #pragma unroll
  for (int jj = 0; jj < 8; ++jj) {
    pf0[jj] = __builtin_nontemporal_load(&pp[jj * 16 + pl]);
    pf1[jj] = __builtin_nontemporal_load(&pp[jj * 16 + 8 + pl]);
  }
  __builtin_amdgcn_sched_barrier(0);   // pin load issue point here

  // 4) contraction into fresh sum regs
  f32x4 s0[8], s1[8];
  #pragma unroll
  for (int jj = 0; jj < 8; ++jj) { s0[jj] = (f32x4)(0.f); s1[jj] = (f32x4)(0.f); }
  const f32x4* t4 = (const f32x4*)&t_lds[0][0];  // [c*16 + pidx]
  const f32x4* s4 = (const f32x4*)&s_lds[0][0];  // [c*64 + jg*2 + {0,1}]
  #pragma unroll 8
  for (int c = 0; c < DM; ++c) {
    f32x4 t0 = t4[c * 16 + pl];
    f32x4 t1 = t4[c * 16 + 8 + pl];
    f32x4 sA = s4[c * 64 + jg * 2];
    f32x4 sB = s4[c * 64 + jg * 2 + 1];
    fma4(s0[0], sA.x, t0); fma4(s1[0], sA.x, t1);
    fma4(s0[1], sA.y, t0); fma4(s1[1], sA.y, t1);
    fma4(s0[2], sA.z, t0); fma4(s1[2], sA.z, t1);
    fma4(s0[3], sA.w, t0); fma4(s1[3], sA.w, t1);
    fma4(s0[4], sB.x, t0); fma4(s1[4], sB.x, t1);
    fma4(s0[5], sB.y, t0); fma4(s1[5], sB.y, t1);
    fma4(s0[6], sB.z, t0); fma4(s1[6], sB.z, t1);
    fma4(s0[7], sB.w, t0); fma4(s1[7], sB.w, t1);
  }

  // 5) epilogue: PLAIN stores (R12 finding: nt stores cost; nt loads win)
  const f32x4* b24 = (const f32x4*)b2;
  f32x4 b0 = b24[pl], b1v = b24[8 + pl];
  f32x4* po = (f32x4*)(out + rowbase);
  #pragma unroll
  for (int jj = 0; jj < 8; ++jj) {
    po[jj * 16 + pl] = s0[jj] + pf0[jj] + b0;
    po[jj * 16 + 8 + pl] = s1[jj] + pf1[jj] + b1v;
  }
}

extern "C" void kernel_launch(void* const* d_in, const int* in_sizes, int n_in,
                              void* d_out, int out_size, void* d_ws, size_t ws_size,
                              hipStream_t stream) {
  const float* seq  = (const float*)d_in[0];
  const float* pair = (const float*)d_in[1];
  const float* W1   = (const float*)d_in[2];
  const float* b1   = (const float*)d_in[3];
  const float* W2   = (const float*)d_in[4];
  const float* b2   = (const float*)d_in[5];
  float* out = (float*)d_out;
  float* sT  = (float*)d_ws;            // 32*1024 floats (128 KB)

  k_proj<<<LSEQ / 4, 256, 0, stream>>>(seq, W1, b1, sT);
  k_main<<<LSEQ * NJT, 256, 0, stream>>>(sT, W2, b2, pair, out);
}

// Round 14
// 100.016 us; speedup vs baseline: 1.3927x; 1.3927x over previous
//
#include <hip/hip_runtime.h>
#include <stdint.h>

#define LSEQ 1024
#define INDIM 256
#define DM 32
#define PD 64
#define JT 256
#define NJT (LSEQ / JT)   // 4

typedef float f32x4 __attribute__((ext_vector_type(4)));

__device__ __forceinline__ void fma4(f32x4& a, float s, const f32x4& t) {
  a.x = fmaf(s, t.x, a.x); a.y = fmaf(s, t.y, a.y);
  a.z = fmaf(s, t.z, a.z); a.w = fmaf(s, t.w, a.w);
}

__device__ __forceinline__ void g2l16(const float* g, float* l) {
  __builtin_amdgcn_global_load_lds(
      (__attribute__((address_space(1))) void*)g,
      (__attribute__((address_space(3))) void*)l, 16, 0, 0);
}

// Prep v2: 512 blocks x 2 rows. Projection (4 d-segments/row) + vectorized
// t-compute: thread=(c=tid>>3, p8=tid&7), f32x4 W2 loads (coalesced), both
// rows accumulated in one W2 pass.
template<bool WRT>
__global__ __launch_bounds__(256) void k_prep2(const float* __restrict__ seq,
    const float* __restrict__ W1, const float* __restrict__ b1,
    const float* __restrict__ W2, float* __restrict__ sT,
    float* __restrict__ t_out) {
  int i0 = blockIdx.x * 2;
  int tid = threadIdx.x;
  __shared__ float srow[2][INDIM];
  __shared__ float part[2][4][DM];
  __shared__ float si[2][DM];
  // load 2 seq rows (512 floats = 128 f32x4)
  if (tid < 128)
    ((f32x4*)&srow[0][0])[tid] =
        ((const f32x4*)(seq + (size_t)i0 * INDIM))[tid];
  __syncthreads();
  {
    // thread: il = tid>>7 (row), dseg = (tid>>5)&3 (4 segs of 64 d), c = tid&31
    int c = tid & 31, dseg = (tid >> 5) & 3, il = tid >> 7;
    float a = 0.f;
    #pragma unroll 16
    for (int d = 0; d < 64; ++d)
      a = fmaf(srow[il][dseg * 64 + d], W1[(dseg * 64 + d) * DM + c], a);
    part[il][dseg][c] = a;
  }
  __syncthreads();
  if (tid < 64) {
    int il = tid >> 5, c = tid & 31;
    float a = b1[c] + part[il][0][c] + part[il][1][c]
                    + part[il][2][c] + part[il][3][c];
    si[il][c] = a;
    sT[c * LSEQ + i0 + il] = a;
  }
  __syncthreads();
  if constexpr (WRT) {
    // thread owns t[c][p8*8..+8) for both rows; W2 reads f32x4-coalesced
    int c = tid >> 3, p8 = tid & 7;
    const f32x4* w2v = (const f32x4*)(W2 + (size_t)(c * DM) * PD + p8 * 8);
    f32x4 a00 = (f32x4)(0.f), a01 = (f32x4)(0.f);
    f32x4 a10 = (f32x4)(0.f), a11 = (f32x4)(0.f);
    #pragma unroll 8
    for (int d = 0; d < DM; ++d) {
      f32x4 wA = w2v[d * 16];
      f32x4 wB = w2v[d * 16 + 1];
      float sv0 = si[0][d], sv1 = si[1][d];
      fma4(a00, sv0, wA); fma4(a01, sv0, wB);
      fma4(a10, sv1, wA); fma4(a11, sv1, wB);
    }
    f32x4* t0 = (f32x4*)(t_out + ((size_t)(i0 + 0) * DM + c) * PD + p8 * 8);
    f32x4* t1 = (f32x4*)(t_out + ((size_t)(i0 + 1) * DM + c) * PD + p8 * 8);
    t0[0] = a00; t0[1] = a01;
    t1[0] = a10; t1[1] = a11;
  }
}

// Champion k_main (R12): g2l staging -> barrier (drains only L2-fast staging)
// -> nt pair loads -> c-loop -> plain stores.
template<bool TPRE>
__global__ __launch_bounds__(256) void k_main(const float* __restrict__ sT,
    const float* __restrict__ tg, const float* __restrict__ W2,
    const float* __restrict__ b2, const float* __restrict__ pair,
    float* __restrict__ out) {
  __shared__ float t_lds[DM][PD];    // 8 KB
  __shared__ float s_lds[DM][JT];    // 32 KB
  int tid = threadIdx.x;
  // XCD-chunked bijective swizzle (4096 % 8 == 0)
  int bid = ((blockIdx.x & 7) << 9) + (blockIdx.x >> 3);
  int i = bid >> 2;
  int jt = (bid & (NJT - 1)) * JT;
  int pl = tid & 7;           // p = pl*4..+3 and 32+pl*4..+3
  int jg = tid >> 3;          // 0..31: j = jt + jg*8 + jj
  int lane = tid & 63, w = tid >> 6;

  // 1) async staging from L2-resident sources
  if constexpr (TPRE) {
    const float* tb = tg + (size_t)i * (DM * PD) + w * 512 + lane * 4;
    float* tl = &t_lds[0][0] + w * 512;
    g2l16(tb, tl);
    g2l16(tb + 256, tl + 256);
  }
  {
    const float* sb = sT + (size_t)(w * 8) * LSEQ + jt + lane * 4;
    float* sl = &s_lds[w * 8][0];
    #pragma unroll
    for (int q = 0; q < 8; ++q)
      g2l16(sb + q * LSEQ, sl + q * JT);
  }
  if constexpr (!TPRE) {
    __shared__ float sish[DM];
    if (tid < DM) sish[tid] = sT[tid * LSEQ + i];
    __syncthreads();
    int p = tid & 63, c0 = tid >> 6;
    #pragma unroll
    for (int k = 0; k < 8; ++k) {
      int c = c0 * 8 + k;
      float acc = 0.f;
      #pragma unroll
      for (int d = 0; d < DM; ++d)
        acc = fmaf(sish[d], W2[(c * DM + d) * PD + p], acc);
      t_lds[c][p] = acc;
    }
  }
  __syncthreads();   // drains g2l staging only (L2 sources, fast)

  // 2) NOW issue pair loads (nontemporal: keep L2 clean for t/sT)
  size_t rowbase = (size_t)i * (LSEQ * PD) + (size_t)(jt + jg * 8) * PD;
  const f32x4* pp = (const f32x4*)(pair + rowbase);
  f32x4 pf0[8], pf1[8];
  #pragma unroll
  for (int jj = 0; jj < 8; ++jj) {
    pf0[jj] = __builtin_nontemporal_load(&pp[jj * 16 + pl]);
    pf1[jj] = __builtin_nontemporal_load(&pp[jj * 16 + 8 + pl]);
  }
  __builtin_amdgcn_sched_barrier(0);   // pin load issue point here

  // 3) contraction into fresh sum regs (independent of the in-flight loads)
  f32x4 s0[8], s1[8];
  #pragma unroll
  for (int jj = 0; jj < 8; ++jj) { s0[jj] = (f32x4)(0.f); s1[jj] = (f32x4)(0.f); }
  const f32x4* t4 = (const f32x4*)&t_lds[0][0];  // [c*16 + pidx]
  const f32x4* s4 = (const f32x4*)&s_lds[0][0];  // [c*64 + jg*2 + {0,1}]
  #pragma unroll 8
  for (int c = 0; c < DM; ++c) {
    f32x4 t0 = t4[c * 16 + pl];
    f32x4 t1 = t4[c * 16 + 8 + pl];
    f32x4 sA = s4[c * 64 + jg * 2];
    f32x4 sB = s4[c * 64 + jg * 2 + 1];
    fma4(s0[0], sA.x, t0); fma4(s1[0], sA.x, t1);
    fma4(s0[1], sA.y, t0); fma4(s1[1], sA.y, t1);
    fma4(s0[2], sA.z, t0); fma4(s1[2], sA.z, t1);
    fma4(s0[3], sA.w, t0); fma4(s1[3], sA.w, t1);
    fma4(s0[4], sB.x, t0); fma4(s1[4], sB.x, t1);
    fma4(s0[5], sB.y, t0); fma4(s1[5], sB.y, t1);
    fma4(s0[6], sB.z, t0); fma4(s1[6], sB.z, t1);
    fma4(s0[7], sB.w, t0); fma4(s1[7], sB.w, t1);
  }

  // 4) epilogue: PLAIN stores (R12 finding: plain stores beat nt stores)
  const f32x4* b24 = (const f32x4*)b2;
  f32x4 b0 = b24[pl], b1v = b24[8 + pl];
  f32x4* po = (f32x4*)(out + rowbase);
  #pragma unroll
  for (int jj = 0; jj < 8; ++jj) {
    po[jj * 16 + pl] = s0[jj] + pf0[jj] + b0;
    po[jj * 16 + 8 + pl] = s1[jj] + pf1[jj] + b1v;
  }
}

extern "C" void kernel_launch(void* const* d_in, const int* in_sizes, int n_in,
                              void* d_out, int out_size, void* d_ws, size_t ws_size,
                              hipStream_t stream) {
  const float* seq  = (const float*)d_in[0];
  const float* pair = (const float*)d_in[1];
  const float* W1   = (const float*)d_in[2];
  const float* b1   = (const float*)d_in[3];
  const float* W2   = (const float*)d_in[4];
  const float* b2   = (const float*)d_in[5];
  float* out = (float*)d_out;
  float* ws  = (float*)d_ws;

  float* sT = ws;                       // 32*1024 floats (128 KB)
  float* t  = ws + DM * LSEQ;           // 1024*32*64 floats (8 MB)
  size_t need = (size_t)(DM * LSEQ + (size_t)LSEQ * DM * PD) * sizeof(float);

  if (ws_size >= need) {
    k_prep2<true><<<LSEQ / 2, 256, 0, stream>>>(seq, W1, b1, W2, sT, t);
    k_main<true><<<LSEQ * NJT, 256, 0, stream>>>(sT, t, W2, b2, pair, out);
  } else {
    k_prep2<false><<<LSEQ / 2, 256, 0, stream>>>(seq, W1, b1, W2, sT, nullptr);
    k_main<false><<<LSEQ * NJT, 256, 0, stream>>>(sT, nullptr, W2, b2, pair, out);
  }
}